// Round 19
// baseline (164.892 us; speedup 1.0000x reference)
//
#include <hip/hip_runtime.h>

typedef float v2f __attribute__((ext_vector_type(2)));

constexpr int NX = 192, NY = 192, NZ = 192, NB = 2;
constexpr int ZPT  = 4;            // z outputs per thread
constexpr int TZ   = NZ / ZPT;     // 48
constexpr int BY   = 4;            // y rows per block
constexpr int XSEG = 4;            // x outputs per block
constexpr int BLOCK_THREADS = TZ * BY;   // 192 = 3 waves
constexpr int PLANE = NY * NZ;
constexpr int NXB = NX / XSEG;     // 48
constexpr int NYB = NY / BY;       // 48
constexpr int NBLK = NYB * NXB * NB;     // 4608 blocks
constexpr int RSTR = 196;                // padded LDS row stride (R13)
constexpr int TILE_F = 2 * 6 * RSTR;     // 2352 floats = 9408 B per buffer

// full-wave DPP shifts (verified on gfx950 in R16/R17, absmax=0):
// bound_ctrl=1 -> zero fill at wave edges.
__device__ __forceinline__ float wshr1(float v) {   // lane n <- lane n-1
    return __int_as_float(__builtin_amdgcn_update_dpp(
        0, __float_as_int(v), 0x138, 0xf, 0xf, true));
}
__device__ __forceinline__ float wshl1(float v) {   // lane n <- lane n+1
    return __int_as_float(__builtin_amdgcn_update_dpp(
        0, __float_as_int(v), 0x130, 0xf, 0xf, true));
}

// Fold one staged x-plane (R13 structure). Edge taps z0-1 / z0+4 come from
// DPP lane exchange of the already-loaded b128 values (lane+-1 holds them),
// eliminating the 12 conflicting 16B-stride b32 LDS reads per plane.
// Exceptions handled exactly:
//  - intra-wave tx-wrap lanes: taps are volume z-boundaries -> wzm/wze = 0
//  - wave-boundary lanes with interior z (fixm/fixe): exec-masked LDS read.
template<bool SAFE>
__device__ __forceinline__ void foldLDS(const float* __restrict__ buf,
    int ty, int z0, int zm, int ze, const float wy[3],
    float wzm, float wze, bool fixm, bool fixe, float wx, v2f W[5][2])
{
    v2f S[5][3];
    #pragma unroll
    for (int r = 0; r < 3; ++r) {
        const float* Lt = buf + (ty + r) * RSTR;        // label row
        const float* Lp = Lt + 6 * RSTR;                // pred row
        const float4 t4 = *reinterpret_cast<const float4*>(Lt + z0);
        const float4 p4 = *reinterpret_cast<const float4*>(Lp + z0);
        float tm = wshr1(t4.w), te = wshl1(t4.x);
        float pm = wshr1(p4.w), pe = wshl1(p4.x);
        if (fixm) { tm = Lt[zm]; pm = Lp[zm]; }   // lane 0 of wave, tx!=0
        if (fixe) { te = Lt[ze]; pe = Lp[ze]; }   // lane 63 of wave, tx!=47
        tm *= wzm; pm *= wzm;                     // {0,1}: volume z-pad exact
        te *= wze; pe *= wze;
        v2f T[3]  = { v2f{tm, t4.x}, v2f{t4.y, t4.z}, v2f{t4.w, te} };
        v2f Pv[3] = { v2f{pm, p4.x}, v2f{p4.y, p4.z}, v2f{p4.w, pe} };
        if (!SAFE) {
            const float wr = wx * wy[r];                // w in {0,1} => exact
            #pragma unroll
            for (int q = 0; q < 3; ++q) { T[q] *= wr; Pv[q] *= wr; }
        }
        #pragma unroll
        for (int q = 0; q < 3; ++q) {
            if (r == 0) {
                S[0][q] = T[q];  S[1][q] = Pv[q];
                S[2][q] = T[q] * T[q];  S[3][q] = Pv[q] * Pv[q];  S[4][q] = T[q] * Pv[q];
            } else {
                S[0][q] += T[q];  S[1][q] += Pv[q];
                S[2][q] += T[q] * T[q];  S[3][q] += Pv[q] * Pv[q];  S[4][q] += T[q] * Pv[q];
            }
        }
    }
    #pragma unroll
    for (int q = 0; q < 5; ++q) {
        const float s0 = S[q][0].x, s1 = S[q][0].y, s2 = S[q][1].x;
        const float s3 = S[q][1].y, s4 = S[q][2].x, s5 = S[q][2].y;
        const float m12 = s1 + s2, m34 = s3 + s4;
        W[q][0] = v2f{s0 + m12, m12 + s3};
        W[q][1] = v2f{s2 + m34, m34 + s5};
    }
}

__device__ __forceinline__ float epilogue4(const v2f P[5][2], const v2f Wn[5][2])
{
    constexpr float inv_vol = 1.0f / 27.0f;
    float acc = 0.f;
    #pragma unroll
    for (int h = 0; h < 2; ++h) {
        const v2f st  = P[0][h] + Wn[0][h];
        const v2f sp  = P[1][h] + Wn[1][h];
        const v2f st2 = P[2][h] + Wn[2][h];
        const v2f sp2 = P[3][h] + Wn[3][h];
        const v2f stp = P[4][h] + Wn[4][h];
        const v2f tavg = st * inv_vol;
        const v2f pavg = sp * inv_vol;
        const v2f cross = stp - pavg * st;
        const v2f tvp   = st2 - tavg * st;
        const v2f pvp   = sp2 - pavg * sp;
        const v2f cc    = cross * cross;
        #pragma unroll
        for (int c = 0; c < 2; ++c) {
            const float tvar = fmaxf(tvp[c], 0.f);
            const float pvar = fmaxf(pvp[c], 0.f);
            acc += cc[c] * __builtin_amdgcn_rcpf(fmaf(tvar, pvar, 1e-5f));
        }
    }
    return acc;
}

// R13's proven 6-plane double-buffered march.
template<bool SAFE>
__device__ __forceinline__ float march(
    const float* sb0, const float* sb1, const float* sb2,
    int lo0, int lo1, int lo2,
    float (*tile)[TILE_F],
    int ty, int z0, int zm, int ze, const float wy[3],
    float wzm, float wze, bool fixm, bool fixe, int xs0)
{
    v2f U[5][2], V[5][2], P[5][2];
    float acc = 0.f;
    float4 G0, G1, G2;

#define XOFF(K) (SAFE ? (xs0 - 1 + (K)) * PLANE \
                      : min(max(xs0 - 1 + (K), 0), NX - 1) * PLANE)
#define WXK(K)  (SAFE ? 1.f : (((unsigned)(xs0 - 1 + (K)) < (unsigned)NX) ? 1.f : 0.f))
#define GLOAD(K) do { const int _xo = XOFF(K);                                  \
        G0 = *reinterpret_cast<const float4*>(sb0 + _xo);                       \
        G1 = *reinterpret_cast<const float4*>(sb1 + _xo);                       \
        G2 = *reinterpret_cast<const float4*>(sb2 + _xo); } while (0)
#define DSWR(K) do { float* _d = tile[(K) & 1];                                 \
        *reinterpret_cast<float4*>(_d + lo0) = G0;                              \
        *reinterpret_cast<float4*>(_d + lo1) = G1;                              \
        *reinterpret_cast<float4*>(_d + lo2) = G2; } while (0)
#define FOLD(K, WDST) foldLDS<SAFE>(tile[(K) & 1], ty, z0, zm, ze, wy,          \
                                    wzm, wze, fixm, fixe, WXK(K), WDST)
#define PSET(A, B) do { _Pragma("unroll")                                       \
        for (int q = 0; q < 5; ++q) { _Pragma("unroll")                         \
            for (int h = 0; h < 2; ++h) P[q][h] = A[q][h] + B[q][h]; } } while (0)

    GLOAD(0); DSWR(0); __syncthreads();
    GLOAD(1); FOLD(0, U);             DSWR(1); __syncthreads();
    GLOAD(2); FOLD(1, V); PSET(U, V); DSWR(2); __syncthreads();
    GLOAD(3); FOLD(2, U); acc += epilogue4(P, U); PSET(V, U); DSWR(3); __syncthreads();
    GLOAD(4); FOLD(3, V); acc += epilogue4(P, V); PSET(U, V); DSWR(4); __syncthreads();
    GLOAD(5); FOLD(4, U); acc += epilogue4(P, U); PSET(V, U); DSWR(5); __syncthreads();
              FOLD(5, V); acc += epilogue4(P, V);

#undef XOFF
#undef WXK
#undef GLOAD
#undef DSWR
#undef FOLD
#undef PSET
    return acc;
}

__global__ __launch_bounds__(BLOCK_THREADS, 3)
void ncc_partial(const float* __restrict__ pred, const float* __restrict__ label,
                 float* __restrict__ partials)
{
    __shared__ alignas(16) float tile[2][TILE_F];    // 18,816 B

    const int tx  = threadIdx.x;
    const int ty  = threadIdx.y;
    const int tid = tx + ty * TZ;
    const int lane = tid & 63;
    const int z0  = tx * ZPT;
    const int y0  = blockIdx.x * BY;
    const int y   = y0 + ty;
    const int xs0 = blockIdx.y * XSEG;
    const int b   = blockIdx.z;
    const int bbase = b * NX * PLANE;

    // staging: flat float4-index j = r*192 + tid over [tensor(2)][row(6)][z4(48)]
    const float* sb[3];
    int lo[3];
    #pragma unroll
    for (int r = 0; r < 3; ++r) {
        const int j   = r * BLOCK_THREADS + tid;
        const int tt  = j / 288, rem = j - tt * 288;
        const int row = rem / 48, z4 = rem - row * 48;
        int grow = y0 - 1 + row;
        grow = min(max(grow, 0), NY - 1);
        sb[r] = (tt ? pred : label) + bbase + grow * NZ + z4 * 4;
        lo[r] = (tt * 6 + row) * RSTR + z4 * 4;
    }

    float wy[3];
    #pragma unroll
    for (int r = 0; r < 3; ++r) {
        const int yy = y + r - 1;
        wy[r] = ((unsigned)yy < (unsigned)NY) ? 1.f : 0.f;
    }
    const float wzm = (tx == 0) ? 0.f : 1.f;
    const float wze = (tx == TZ - 1) ? 0.f : 1.f;
    // wave-boundary lanes whose z-neighbors live in another wave:
    const bool fixm = (lane == 0)  && (tx != 0);
    const bool fixe = (lane == 63) && (tx != TZ - 1);
    // clamped fallback addresses (in-bounds even on non-fix lanes if hoisted)
    const int zm = (tx == 0) ? 0 : z0 - 1;
    const int ze = z0 + 4;                 // <=192, in-bounds (RSTR=196 row)

    const bool safe = (blockIdx.x >= 1) && (blockIdx.x <= NYB - 2) &&
                      (blockIdx.y >= 1) && (blockIdx.y <= NXB - 2);

    const float acc = safe
        ? march<true >(sb[0], sb[1], sb[2], lo[0], lo[1], lo[2], tile,
                       ty, z0, zm, ze, wy, wzm, wze, fixm, fixe, xs0)
        : march<false>(sb[0], sb[1], sb[2], lo[0], lo[1], lo[2], tile,
                       ty, z0, zm, ze, wy, wzm, wze, fixm, fixe, xs0);

    // wave (64) reduction, then block sum
    float a = acc;
    #pragma unroll
    for (int o = 32; o > 0; o >>= 1)
        a += __shfl_down(a, o, 64);

    __shared__ float wsum[BLOCK_THREADS / 64];
    if ((tid & 63) == 0) wsum[tid >> 6] = a;
    __syncthreads();
    if (tid == 0) {
        float s = 0.f;
        #pragma unroll
        for (int w = 0; w < BLOCK_THREADS / 64; ++w) s += wsum[w];
        partials[blockIdx.x + (int)gridDim.x * (blockIdx.y + (int)gridDim.y * blockIdx.z)] = s;
    }
}

__global__ __launch_bounds__(256)
void ncc_reduce(const float* __restrict__ partials, int n, float* __restrict__ out)
{
    __shared__ double sh[256];
    double s = 0.0;
    for (int i = threadIdx.x; i < n; i += 256) s += (double)partials[i];
    sh[threadIdx.x] = s;
    __syncthreads();
    for (int off = 128; off > 0; off >>= 1) {
        if ((int)threadIdx.x < off) sh[threadIdx.x] += sh[threadIdx.x + off];
        __syncthreads();
    }
    if (threadIdx.x == 0) {
        const double nvox = (double)NB * NX * NY * NZ;
        out[0] = (float)(-sh[0] / nvox);
    }
}

extern "C" void kernel_launch(void* const* d_in, const int* in_sizes, int n_in,
                              void* d_out, int out_size, void* d_ws, size_t ws_size,
                              hipStream_t stream) {
    const float* pred  = (const float*)d_in[0];
    const float* label = (const float*)d_in[1];
    float* out = (float*)d_out;
    float* partials = (float*)d_ws;

    dim3 block(TZ, BY, 1);                 // 48 x 4 = 192 threads
    dim3 grid(NYB, NXB, NB);               // 48 x 48 x 2 = 4608 blocks

    ncc_partial<<<grid, block, 0, stream>>>(pred, label, partials);
    ncc_reduce<<<1, 256, 0, stream>>>(partials, NBLK, out);
}

// Round 20
// 164.678 us; speedup vs baseline: 1.0013x; 1.0013x over previous
//
#include <hip/hip_runtime.h>

typedef float v2f __attribute__((ext_vector_type(2)));

constexpr int NX = 192, NY = 192, NZ = 192, NB = 2;
constexpr int ZPT  = 4;            // z outputs per (live) thread
constexpr int TZL  = 48;           // live z-chunks per row
constexpr int TZ   = 64;           // padded: wave = exactly one y-row
constexpr int BY   = 4;            // y rows per block (one per wave)
constexpr int XSEG = 4;            // x outputs per block
constexpr int BLOCK_THREADS = TZ * BY;   // 256 = 4 waves
constexpr int PLANE = NY * NZ;
constexpr int NXB = NX / XSEG;     // 48
constexpr int NYB = NY / BY;       // 48
constexpr int NBLK = NYB * NXB * NB;     // 4608 blocks
constexpr int RSTR = 196;                // LDS row stride (R13)
constexpr int TILE_F = 2 * 6 * RSTR;     // 2352 floats = 9408 B per buffer
constexpr int SUNITS = 2 * 6 * TZL;      // 576 float4 staging units

// full-wave DPP shifts (gfx950-verified in R16/R17, absmax=0):
// bound_ctrl=1 -> zero fill at wave edges (= volume z-edges here).
__device__ __forceinline__ float wshr1(float v) {   // lane n <- lane n-1
    return __int_as_float(__builtin_amdgcn_update_dpp(
        0, __float_as_int(v), 0x138, 0xf, 0xf, true));
}
__device__ __forceinline__ float wshl1(float v) {   // lane n <- lane n+1
    return __int_as_float(__builtin_amdgcn_update_dpp(
        0, __float_as_int(v), 0x130, 0xf, 0xf, true));
}

// Fold one staged x-plane. Wave == one y-row: the 2 b128 reads per row-tensor
// are lane-sequential (canonical conflict-free pattern); edge taps z0-1/z0+4
// via DPP of neighbor lanes' already-loaded values. No divergence, no b32
// reads. Lanes 48-63 are dead (clamped addresses, result masked by caller).
template<bool SAFE>
__device__ __forceinline__ void foldLDS(const float* __restrict__ buf,
    int ty, int z0, const float wy[3], float wzm, float wze, float wx,
    v2f W[5][2])
{
    v2f S[5][3];
    #pragma unroll
    for (int r = 0; r < 3; ++r) {
        const float* Lt = buf + (ty + r) * RSTR;        // label row
        const float* Lp = Lt + 6 * RSTR;                // pred row
        const float4 t4 = *reinterpret_cast<const float4*>(Lt + z0);
        const float4 p4 = *reinterpret_cast<const float4*>(Lp + z0);
        const float tm = wshr1(t4.w) * wzm, te = wshl1(t4.x) * wze;
        const float pm = wshr1(p4.w) * wzm, pe = wshl1(p4.x) * wze;
        v2f T[3]  = { v2f{tm, t4.x}, v2f{t4.y, t4.z}, v2f{t4.w, te} };
        v2f Pv[3] = { v2f{pm, p4.x}, v2f{p4.y, p4.z}, v2f{p4.w, pe} };
        if (!SAFE) {
            const float wr = wx * wy[r];                // w in {0,1} => exact
            #pragma unroll
            for (int q = 0; q < 3; ++q) { T[q] *= wr; Pv[q] *= wr; }
        }
        #pragma unroll
        for (int q = 0; q < 3; ++q) {
            if (r == 0) {
                S[0][q] = T[q];  S[1][q] = Pv[q];
                S[2][q] = T[q] * T[q];  S[3][q] = Pv[q] * Pv[q];  S[4][q] = T[q] * Pv[q];
            } else {
                S[0][q] += T[q];  S[1][q] += Pv[q];
                S[2][q] += T[q] * T[q];  S[3][q] += Pv[q] * Pv[q];  S[4][q] += T[q] * Pv[q];
            }
        }
    }
    #pragma unroll
    for (int q = 0; q < 5; ++q) {
        const float s0 = S[q][0].x, s1 = S[q][0].y, s2 = S[q][1].x;
        const float s3 = S[q][1].y, s4 = S[q][2].x, s5 = S[q][2].y;
        const float m12 = s1 + s2, m34 = s3 + s4;
        W[q][0] = v2f{s0 + m12, m12 + s3};
        W[q][1] = v2f{s2 + m34, m34 + s5};
    }
}

__device__ __forceinline__ float epilogue4(const v2f P[5][2], const v2f Wn[5][2])
{
    constexpr float inv_vol = 1.0f / 27.0f;
    float acc = 0.f;
    #pragma unroll
    for (int h = 0; h < 2; ++h) {
        const v2f st  = P[0][h] + Wn[0][h];
        const v2f sp  = P[1][h] + Wn[1][h];
        const v2f st2 = P[2][h] + Wn[2][h];
        const v2f sp2 = P[3][h] + Wn[3][h];
        const v2f stp = P[4][h] + Wn[4][h];
        const v2f tavg = st * inv_vol;
        const v2f pavg = sp * inv_vol;
        const v2f cross = stp - pavg * st;
        const v2f tvp   = st2 - tavg * st;
        const v2f pvp   = sp2 - pavg * sp;
        const v2f cc    = cross * cross;
        #pragma unroll
        for (int c = 0; c < 2; ++c) {
            const float tvar = fmaxf(tvp[c], 0.f);
            const float pvar = fmaxf(pvp[c], 0.f);
            acc += cc[c] * __builtin_amdgcn_rcpf(fmaf(tvar, pvar, 1e-5f));
        }
    }
    return acc;
}

// R13's proven 6-plane double-buffered march; 2 staging units/thread + a
// wave-uniform third for wave 0 (576 units over 256 threads).
template<bool SAFE>
__device__ __forceinline__ float march(
    const float* sb0, const float* sb1, const float* sb2, bool do3,
    int lo0, int lo1, int lo2,
    float (*tile)[TILE_F],
    int ty, int z0, const float wy[3], float wzm, float wze, int xs0)
{
    v2f U[5][2], V[5][2], P[5][2];
    float acc = 0.f;
    float4 G0, G1, G2;

#define XOFF(K) (SAFE ? (xs0 - 1 + (K)) * PLANE \
                      : min(max(xs0 - 1 + (K), 0), NX - 1) * PLANE)
#define WXK(K)  (SAFE ? 1.f : (((unsigned)(xs0 - 1 + (K)) < (unsigned)NX) ? 1.f : 0.f))
#define GLOAD(K) do { const int _xo = XOFF(K);                                  \
        G0 = *reinterpret_cast<const float4*>(sb0 + _xo);                       \
        G1 = *reinterpret_cast<const float4*>(sb1 + _xo);                       \
        if (do3) G2 = *reinterpret_cast<const float4*>(sb2 + _xo); } while (0)
#define DSWR(K) do { float* _d = tile[(K) & 1];                                 \
        *reinterpret_cast<float4*>(_d + lo0) = G0;                              \
        *reinterpret_cast<float4*>(_d + lo1) = G1;                              \
        if (do3) *reinterpret_cast<float4*>(_d + lo2) = G2; } while (0)
#define FOLD(K, WDST) foldLDS<SAFE>(tile[(K) & 1], ty, z0, wy, wzm, wze, WXK(K), WDST)
#define PSET(A, B) do { _Pragma("unroll")                                       \
        for (int q = 0; q < 5; ++q) { _Pragma("unroll")                         \
            for (int h = 0; h < 2; ++h) P[q][h] = A[q][h] + B[q][h]; } } while (0)

    GLOAD(0); DSWR(0); __syncthreads();
    GLOAD(1); FOLD(0, U);             DSWR(1); __syncthreads();
    GLOAD(2); FOLD(1, V); PSET(U, V); DSWR(2); __syncthreads();
    GLOAD(3); FOLD(2, U); acc += epilogue4(P, U); PSET(V, U); DSWR(3); __syncthreads();
    GLOAD(4); FOLD(3, V); acc += epilogue4(P, V); PSET(U, V); DSWR(4); __syncthreads();
    GLOAD(5); FOLD(4, U); acc += epilogue4(P, U); PSET(V, U); DSWR(5); __syncthreads();
              FOLD(5, V); acc += epilogue4(P, V);

#undef XOFF
#undef WXK
#undef GLOAD
#undef DSWR
#undef FOLD
#undef PSET
    return acc;
}

__global__ __launch_bounds__(BLOCK_THREADS, 3)
void ncc_partial(const float* __restrict__ pred, const float* __restrict__ label,
                 float* __restrict__ partials)
{
    __shared__ alignas(16) float tile[2][TILE_F];    // 18,816 B

    const int tx  = threadIdx.x;                     // 0..63: lane == z-chunk
    const int ty  = threadIdx.y;                     // 0..3:  y row == wave
    const int tid = tx + ty * TZ;
    const int z0  = min(tx, TZL - 1) * ZPT;          // dead lanes clamp (masked)
    const int y0  = blockIdx.x * BY;
    const int y   = y0 + ty;
    const int xs0 = blockIdx.y * XSEG;
    const int b   = blockIdx.z;
    const int bbase = b * NX * PLANE;

    // staging: 576 float4 units = [tensor(2)][row(6)][z4(48)]; 2/thread + a
    // wave-0-uniform third (tid < 64).
    const float* sb[3];
    int lo[3];
    #pragma unroll
    for (int k = 0; k < 3; ++k) {
        const int u  = tid + k * BLOCK_THREADS;
        const int uu = (u < SUNITS) ? u : 0;
        const int tt  = uu / 288, rem = uu - tt * 288;
        const int row = rem / 48, z4 = rem - row * 48;
        int grow = y0 - 1 + row;
        grow = min(max(grow, 0), NY - 1);
        sb[k] = (tt ? pred : label) + bbase + grow * NZ + z4 * 4;
        lo[k] = (tt * 6 + row) * RSTR + z4 * 4;
    }
    const bool do3 = (tid < SUNITS - 2 * BLOCK_THREADS);   // tid < 64: wave 0 only

    float wy[3];
    #pragma unroll
    for (int r = 0; r < 3; ++r) {
        const int yy = y + r - 1;
        wy[r] = ((unsigned)yy < (unsigned)NY) ? 1.f : 0.f;
    }
    const float wzm = (tx == 0)        ? 0.f : 1.f;   // lane 0 == z=0 edge
    const float wze = (tx >= TZL - 1)  ? 0.f : 1.f;   // tx=47 == z=191 edge (+dead)

    const bool safe = (blockIdx.x >= 1) && (blockIdx.x <= NYB - 2) &&
                      (blockIdx.y >= 1) && (blockIdx.y <= NXB - 2);

    float acc = safe
        ? march<true >(sb[0], sb[1], sb[2], do3, lo[0], lo[1], lo[2], tile,
                       ty, z0, wy, wzm, wze, xs0)
        : march<false>(sb[0], sb[1], sb[2], do3, lo[0], lo[1], lo[2], tile,
                       ty, z0, wy, wzm, wze, xs0);

    // kill dead lanes, then wave (64) reduction + block sum
    acc *= (tx < TZL) ? 1.f : 0.f;
    #pragma unroll
    for (int o = 32; o > 0; o >>= 1)
        acc += __shfl_down(acc, o, 64);

    __shared__ float wsum[BLOCK_THREADS / 64];
    if ((tid & 63) == 0) wsum[tid >> 6] = acc;
    __syncthreads();
    if (tid == 0) {
        float s = 0.f;
        #pragma unroll
        for (int w = 0; w < BLOCK_THREADS / 64; ++w) s += wsum[w];
        partials[blockIdx.x + (int)gridDim.x * (blockIdx.y + (int)gridDim.y * blockIdx.z)] = s;
    }
}

__global__ __launch_bounds__(256)
void ncc_reduce(const float* __restrict__ partials, int n, float* __restrict__ out)
{
    __shared__ double sh[256];
    double s = 0.0;
    for (int i = threadIdx.x; i < n; i += 256) s += (double)partials[i];
    sh[threadIdx.x] = s;
    __syncthreads();
    for (int off = 128; off > 0; off >>= 1) {
        if ((int)threadIdx.x < off) sh[threadIdx.x] += sh[threadIdx.x + off];
        __syncthreads();
    }
    if (threadIdx.x == 0) {
        const double nvox = (double)NB * NX * NY * NZ;
        out[0] = (float)(-sh[0] / nvox);
    }
}

extern "C" void kernel_launch(void* const* d_in, const int* in_sizes, int n_in,
                              void* d_out, int out_size, void* d_ws, size_t ws_size,
                              hipStream_t stream) {
    const float* pred  = (const float*)d_in[0];
    const float* label = (const float*)d_in[1];
    float* out = (float*)d_out;
    float* partials = (float*)d_ws;

    dim3 block(TZ, BY, 1);                 // 64 x 4 = 256 threads
    dim3 grid(NYB, NXB, NB);               // 48 x 48 x 2 = 4608 blocks

    ncc_partial<<<grid, block, 0, stream>>>(pred, label, partials);
    ncc_reduce<<<1, 256, 0, stream>>>(partials, NBLK, out);
}

// Round 21
// 49.749 us; speedup vs baseline: 3.3145x; 3.3102x over previous
//
#include <hip/hip_runtime.h>

typedef float v2f __attribute__((ext_vector_type(2)));

constexpr int NX = 192, NY = 192, NZ = 192, NB = 2;
constexpr int ZPT  = 4;            // z outputs per thread
constexpr int TZ   = NZ / ZPT;     // 48
constexpr int BY   = 4;            // y rows per block
constexpr int XSEG = 4;            // x outputs per block
constexpr int BLOCK_THREADS = TZ * BY;   // 192 = 3 waves
constexpr int PLANE = NY * NZ;
constexpr int NXB = NX / XSEG;     // 48
constexpr int NYB = NY / BY;       // 48
constexpr int NBLK = NYB * NXB * NB;     // 4608 blocks
constexpr int RSTR = 196;                // padded LDS row stride (192+4), 16B-aligned
constexpr int TILE_F = 2 * 6 * RSTR;     // 2352 floats = 9408 B per buffer

// Fold one staged x-plane from LDS (proven R13 structure, 49.4 us).
template<bool SAFE>
__device__ __forceinline__ void foldLDS(const float* __restrict__ buf,
    int ty, int z0, const float wy[3], int dm, int de, float wzm, float wze,
    float wx, v2f W[5][2])
{
    v2f S[5][3];
    #pragma unroll
    for (int r = 0; r < 3; ++r) {
        const float* Lt = buf + (ty + r) * RSTR;        // label row
        const float* Lp = Lt + 6 * RSTR;                // pred row
        const float4 t4 = *reinterpret_cast<const float4*>(Lt + z0);
        const float4 p4 = *reinterpret_cast<const float4*>(Lp + z0);
        const float tm = Lt[z0 - dm] * wzm, te = Lt[z0 + de] * wze;
        const float pm = Lp[z0 - dm] * wzm, pe = Lp[z0 + de] * wze;
        v2f T[3]  = { v2f{tm, t4.x}, v2f{t4.y, t4.z}, v2f{t4.w, te} };
        v2f Pv[3] = { v2f{pm, p4.x}, v2f{p4.y, p4.z}, v2f{p4.w, pe} };
        if (!SAFE) {
            const float wr = wx * wy[r];                // w in {0,1} => exact
            #pragma unroll
            for (int q = 0; q < 3; ++q) { T[q] *= wr; Pv[q] *= wr; }
        }
        #pragma unroll
        for (int q = 0; q < 3; ++q) {
            if (r == 0) {
                S[0][q] = T[q];  S[1][q] = Pv[q];
                S[2][q] = T[q] * T[q];  S[3][q] = Pv[q] * Pv[q];  S[4][q] = T[q] * Pv[q];
            } else {
                S[0][q] += T[q];  S[1][q] += Pv[q];
                S[2][q] += T[q] * T[q];  S[3][q] += Pv[q] * Pv[q];  S[4][q] += T[q] * Pv[q];
            }
        }
    }
    #pragma unroll
    for (int q = 0; q < 5; ++q) {
        const float s0 = S[q][0].x, s1 = S[q][0].y, s2 = S[q][1].x;
        const float s3 = S[q][1].y, s4 = S[q][2].x, s5 = S[q][2].y;
        const float m12 = s1 + s2, m34 = s3 + s4;
        W[q][0] = v2f{s0 + m12, m12 + s3};
        W[q][1] = v2f{s2 + m34, m34 + s5};
    }
}

__device__ __forceinline__ float epilogue4(const v2f P[5][2], const v2f Wn[5][2])
{
    constexpr float inv_vol = 1.0f / 27.0f;
    float acc = 0.f;
    #pragma unroll
    for (int h = 0; h < 2; ++h) {
        const v2f st  = P[0][h] + Wn[0][h];
        const v2f sp  = P[1][h] + Wn[1][h];
        const v2f st2 = P[2][h] + Wn[2][h];
        const v2f sp2 = P[3][h] + Wn[3][h];
        const v2f stp = P[4][h] + Wn[4][h];
        const v2f tavg = st * inv_vol;
        const v2f pavg = sp * inv_vol;
        const v2f cross = stp - pavg * st;
        const v2f tvp   = st2 - tavg * st;
        const v2f pvp   = sp2 - pavg * sp;
        const v2f cc    = cross * cross;
        #pragma unroll
        for (int c = 0; c < 2; ++c) {
            const float tvar = fmaxf(tvp[c], 0.f);
            const float pvar = fmaxf(pvp[c], 0.f);
            acc += cc[c] * __builtin_amdgcn_rcpf(fmaf(tvar, pvar, 1e-5f));
        }
    }
    return acc;
}

// March over XSEG+2 = 6 x-planes with double-buffered LDS staging.
template<bool SAFE>
__device__ __forceinline__ float march(
    const float* sb0, const float* sb1, const float* sb2,   // staging srcs (sans x)
    int lo0, int lo1, int lo2,                              // LDS float offsets
    float (*tile)[TILE_F],
    int ty, int z0, const float wy[3],
    int dm, int de, float wzm, float wze, int xs0)
{
    v2f U[5][2], V[5][2], P[5][2];
    float acc = 0.f;
    float4 G0, G1, G2;

#define XOFF(K) (SAFE ? (xs0 - 1 + (K)) * PLANE \
                      : min(max(xs0 - 1 + (K), 0), NX - 1) * PLANE)
#define WXK(K)  (SAFE ? 1.f : (((unsigned)(xs0 - 1 + (K)) < (unsigned)NX) ? 1.f : 0.f))
#define GLOAD(K) do { const int _xo = XOFF(K);                                  \
        G0 = *reinterpret_cast<const float4*>(sb0 + _xo);                       \
        G1 = *reinterpret_cast<const float4*>(sb1 + _xo);                       \
        G2 = *reinterpret_cast<const float4*>(sb2 + _xo); } while (0)
#define DSWR(K) do { float* _d = tile[(K) & 1];                                 \
        *reinterpret_cast<float4*>(_d + lo0) = G0;                              \
        *reinterpret_cast<float4*>(_d + lo1) = G1;                              \
        *reinterpret_cast<float4*>(_d + lo2) = G2; } while (0)
#define FOLD(K, WDST) foldLDS<SAFE>(tile[(K) & 1], ty, z0, wy, dm, de, wzm, wze, WXK(K), WDST)
#define PSET(A, B) do { _Pragma("unroll")                                       \
        for (int q = 0; q < 5; ++q) { _Pragma("unroll")                         \
            for (int h = 0; h < 2; ++h) P[q][h] = A[q][h] + B[q][h]; } } while (0)

    GLOAD(0); DSWR(0); __syncthreads();
    GLOAD(1); FOLD(0, U);             DSWR(1); __syncthreads();
    GLOAD(2); FOLD(1, V); PSET(U, V); DSWR(2); __syncthreads();
    GLOAD(3); FOLD(2, U); acc += epilogue4(P, U); PSET(V, U); DSWR(3); __syncthreads();
    GLOAD(4); FOLD(3, V); acc += epilogue4(P, V); PSET(U, V); DSWR(4); __syncthreads();
    GLOAD(5); FOLD(4, U); acc += epilogue4(P, U); PSET(V, U); DSWR(5); __syncthreads();
              FOLD(5, V); acc += epilogue4(P, V);

#undef XOFF
#undef WXK
#undef GLOAD
#undef DSWR
#undef FOLD
#undef PSET
    return acc;
}

__global__ __launch_bounds__(BLOCK_THREADS, 3)
void ncc_partial(const float* __restrict__ pred, const float* __restrict__ label,
                 float* __restrict__ partials)
{
    __shared__ alignas(16) float tile[2][TILE_F];    // 18,816 B

    const int tx  = threadIdx.x;
    const int ty  = threadIdx.y;
    const int tid = tx + ty * TZ;
    const int z0  = tx * ZPT;
    const int y0  = blockIdx.x * BY;
    const int y   = y0 + ty;
    const int xs0 = blockIdx.y * XSEG;
    const int b   = blockIdx.z;
    const int bbase = b * NX * PLANE;

    // staging: flat float4-index j = r*192 + tid over [tensor(2)][row(6)][z4(48)]
    const float* sb[3];
    int lo[3];
    #pragma unroll
    for (int r = 0; r < 3; ++r) {
        const int j   = r * BLOCK_THREADS + tid;
        const int tt  = j / 288, rem = j - tt * 288;
        const int row = rem / 48, z4 = rem - row * 48;
        int grow = y0 - 1 + row;
        grow = min(max(grow, 0), NY - 1);
        sb[r] = (tt ? pred : label) + bbase + grow * NZ + z4 * 4;
        lo[r] = (tt * 6 + row) * RSTR + z4 * 4;
    }

    float wy[3];
    #pragma unroll
    for (int r = 0; r < 3; ++r) {
        const int yy = y + r - 1;
        wy[r] = ((unsigned)yy < (unsigned)NY) ? 1.f : 0.f;
    }
    const int   dm  = (tx == 0) ? 0 : 1;
    const int   de  = (tx == TZ - 1) ? 0 : ZPT;
    const float wzm = (tx == 0) ? 0.f : 1.f;
    const float wze = (tx == TZ - 1) ? 0.f : 1.f;

    const bool safe = (blockIdx.x >= 1) && (blockIdx.x <= NYB - 2) &&
                      (blockIdx.y >= 1) && (blockIdx.y <= NXB - 2);

    const float acc = safe
        ? march<true >(sb[0], sb[1], sb[2], lo[0], lo[1], lo[2], tile,
                       ty, z0, wy, dm, de, wzm, wze, xs0)
        : march<false>(sb[0], sb[1], sb[2], lo[0], lo[1], lo[2], tile,
                       ty, z0, wy, dm, de, wzm, wze, xs0);

    // wave (64) reduction, then block sum
    float a = acc;
    #pragma unroll
    for (int o = 32; o > 0; o >>= 1)
        a += __shfl_down(a, o, 64);

    __shared__ float wsum[BLOCK_THREADS / 64];
    if ((tid & 63) == 0) wsum[tid >> 6] = a;
    __syncthreads();
    if (tid == 0) {
        float s = 0.f;
        #pragma unroll
        for (int w = 0; w < BLOCK_THREADS / 64; ++w) s += wsum[w];
        partials[blockIdx.x + (int)gridDim.x * (blockIdx.y + (int)gridDim.y * blockIdx.z)] = s;
    }
}

__global__ __launch_bounds__(256)
void ncc_reduce(const float* __restrict__ partials, int n, float* __restrict__ out)
{
    __shared__ double sh[256];
    double s = 0.0;
    for (int i = threadIdx.x; i < n; i += 256) s += (double)partials[i];
    sh[threadIdx.x] = s;
    __syncthreads();
    for (int off = 128; off > 0; off >>= 1) {
        if ((int)threadIdx.x < off) sh[threadIdx.x] += sh[threadIdx.x + off];
        __syncthreads();
    }
    if (threadIdx.x == 0) {
        const double nvox = (double)NB * NX * NY * NZ;
        out[0] = (float)(-sh[0] / nvox);
    }
}

extern "C" void kernel_launch(void* const* d_in, const int* in_sizes, int n_in,
                              void* d_out, int out_size, void* d_ws, size_t ws_size,
                              hipStream_t stream) {
    const float* pred  = (const float*)d_in[0];
    const float* label = (const float*)d_in[1];
    float* out = (float*)d_out;
    float* partials = (float*)d_ws;

    dim3 block(TZ, BY, 1);                 // 48 x 4 = 192 threads
    dim3 grid(NYB, NXB, NB);               // 48 x 48 x 2 = 4608 blocks

    ncc_partial<<<grid, block, 0, stream>>>(pred, label, partials);
    ncc_reduce<<<1, 256, 0, stream>>>(partials, NBLK, out);
}